// Round 7
// baseline (36.303 us; speedup 1.0000x reference)
//
#include <hip/hip_runtime.h>

#define NN 16384
#define NT 1024

__global__ __launch_bounds__(NT) void dag_eval_kernel(
    const int* __restrict__ left,
    const int* __restrict__ right,
    const unsigned char* __restrict__ reroll_raw,
    int* __restrict__ out)
{
    __shared__ __align__(16) unsigned char reach[NN];       // 0/1 bytes
    __shared__ __align__(16) unsigned char state[NN + 16];  // hs|hr<<1|fin<<2; [NN..]=4
    __shared__ int flags[4];
    __shared__ int nzmask;
    __shared__ int cnt;

    const int tid = threadIdx.x;

    if (tid < 4)  flags[tid] = 0;
    if (tid == 0) { nzmask = 0; cnt = 0; }
    if (tid < 16) state[NN + tid] = 4;

    // ---- children for strided nodes (node = tid + k*NT): coalesced scalar loads ----
    unsigned int cpair[16];
    #pragma unroll
    for (int k = 0; k < 16; ++k) {
        int l = left[tid + k * NT];
        int r = right[tid + k * NT];
        cpair[k] = (l & 0xFFFFu) | ((unsigned)r << 16);
    }

    // ---- leaf_is_reroll layout probe (first 16 KB safe for all layouts) ----
    {
        uint4 v = ((const uint4*)reroll_raw)[tid];
        unsigned int t = v.x | v.y | v.z | v.w;
        unsigned int m = 0;
        if (t & 0x000000FFu) m |= 1u;
        if (t & 0x0000FF00u) m |= 2u;
        if (t & 0x00FF0000u) m |= 4u;
        if (t & 0xFF000000u) m |= 8u;
        if (m) atomicOr(&nzmask, (int)m);
    }
    *(uint4*)&reach[tid * 16] = make_uint4(0u, 0u, 0u, 0u);
    __syncthreads();

    const int mask   = nzmask;
    const int layout = ((mask & ~1) == 0) ? 0 : (((mask & 3) == 0) ? 1 : 2);
    const int*   ri = (const int*)reroll_raw;
    const float* rf = (const float*)reroll_raw;

    // ---- backward state init from leaf children (strided nodes) ----
    int sreg[16];
    unsigned int todo = 0;
    #pragma unroll
    for (int k = 0; k < 16; ++k) {
        int c0 = (int)(short)(cpair[k] & 0xFFFFu);
        int c1 = (int)(short)(cpair[k] >> 16);
        int s = 0;
        if (c0 < 0) {
            int id = -c0 - 1;
            bool rr = (layout == 2) ? (reroll_raw[id] != 0)
                     : (layout == 1) ? (rf[id] != 0.0f)
                                     : (ri[id] != 0);
            s |= rr ? 2 : 1;
        }
        if (c1 < 0) {
            int id = -c1 - 1;
            bool rr = (layout == 2) ? (reroll_raw[id] != 0)
                     : (layout == 1) ? (rf[id] != 0.0f)
                                     : (ri[id] != 0);
            s |= rr ? 2 : 1;
        }
        if ((c0 < 0 && c1 < 0) || s == 3) s |= 4;
        else todo |= 1u << k;
        sreg[k] = s;
        state[tid + k * NT] = (unsigned char)s;
    }
    if (tid == 0) reach[0] = 1;
    __syncthreads();

    // ---- merged fixpoint, Gauss-Seidel-ordered within each sweep ----
    unsigned int pushed = 0;
    for (int w = 0; w < 600; ++w) {
        bool ch = false;

        // forward: ascending k-pairs (top-down GS within the sweep)
        #pragma unroll
        for (int kp = 0; kp < 8; ++kp) {
            const int k0 = 2 * kp, k1 = 2 * kp + 1;
            unsigned int need = (~pushed >> k0) & 3u;
            if (need) {
                int r0 = (need & 1u) ? (int)reach[tid + k0 * NT] : 0;
                int r1 = (need & 2u) ? (int)reach[tid + k1 * NT] : 0;
                if (r0) {
                    pushed |= 1u << k0; ch = true;
                    int c0 = (int)(short)(cpair[k0] & 0xFFFFu);
                    int c1 = (int)(short)(cpair[k0] >> 16);
                    if (c0 > 0) reach[c0] = (unsigned char)1;
                    if (c1 > 0) reach[c1] = (unsigned char)1;
                }
                if (r1) {
                    pushed |= 1u << k1; ch = true;
                    int c0 = (int)(short)(cpair[k1] & 0xFFFFu);
                    int c1 = (int)(short)(cpair[k1] >> 16);
                    if (c0 > 0) reach[c0] = (unsigned char)1;
                    if (c1 > 0) reach[c1] = (unsigned char)1;
                }
            }
        }

        // backward: descending k-pairs (bottom-up GS within the sweep)
        if (todo) {
            #pragma unroll
            for (int kp = 7; kp >= 0; --kp) {
                const int k0 = 2 * kp, k1 = 2 * kp + 1;
                if ((todo >> k0) & 3u) {
                    bool a1 = (todo >> k1) & 1u;
                    bool a0 = (todo >> k0) & 1u;
                    int c10 = (int)(short)(cpair[k1] & 0xFFFFu);
                    int c11 = (int)(short)(cpair[k1] >> 16);
                    int c00 = (int)(short)(cpair[k0] & 0xFFFFu);
                    int c01 = (int)(short)(cpair[k0] >> 16);
                    int sl1 = state[(a1 && c10 > 0) ? c10 : NN];
                    int sr1 = state[(a1 && c11 > 0) ? c11 : NN];
                    int sl0 = state[(a0 && c00 > 0) ? c00 : NN];
                    int sr0 = state[(a0 && c01 > 0) ? c01 : NN];
                    if (a1) {
                        int ns = sreg[k1] | (sl1 & 3) | (sr1 & 3);
                        bool fin = ((sl1 & sr1 & 4) != 0) || ((ns & 3) == 3);
                        if (fin) { ns |= 4; todo &= ~(1u << k1); }
                        if (ns != sreg[k1]) {
                            sreg[k1] = ns;
                            state[tid + k1 * NT] = (unsigned char)ns;
                            ch = true;
                        }
                    }
                    if (a0) {
                        int ns = sreg[k0] | (sl0 & 3) | (sr0 & 3);
                        bool fin = ((sl0 & sr0 & 4) != 0) || ((ns & 3) == 3);
                        if (fin) { ns |= 4; todo &= ~(1u << k0); }
                        if (ns != sreg[k0]) {
                            sreg[k0] = ns;
                            state[tid + k0 * NT] = (unsigned char)ns;
                            ch = true;
                        }
                    }
                }
            }
        }

        if (ch) flags[w & 3] = 1;
        __syncthreads();                       // single barrier per sweep
        int f = flags[w & 3];
        if (tid == 0) flags[(w + 2) & 3] = 0;  // >=1 barrier before slot reuse
        if (!f) break;
    }

    // ---- count: linear read of reach, byte-sum trick, one atomic per wave ----
    uint4 v = *(const uint4*)&reach[tid * 16];
    {
        unsigned int t = v.x + v.y + v.z + v.w;   // per-byte lanes <= 4
        int cc = (t & 0xFF) + ((t >> 8) & 0xFF) + ((t >> 16) & 0xFF) + (t >> 24);
        #pragma unroll
        for (int off = 32; off; off >>= 1) cc += __shfl_down(cc, off);
        if ((tid & 63) == 0) atomicAdd(&cnt, cc);
    }

    // ---- outputs: linear reads of reach/state, int4 stores ----
    int4* out4 = (int4*)out;
    {
        unsigned int wd[4] = {v.x, v.y, v.z, v.w};
        #pragma unroll
        for (int j = 0; j < 4; ++j) {
            int4 a;
            a.x = (wd[j] >> 0)  & 1;
            a.y = (wd[j] >> 8)  & 1;
            a.z = (wd[j] >> 16) & 1;
            a.w = (wd[j] >> 24) & 1;
            out4[(tid * 16 >> 2) + j] = a;
        }
    }
    {
        uint4 sv = *(const uint4*)&state[tid * 16];
        unsigned int wd[4] = {sv.x, sv.y, sv.z, sv.w};
        #pragma unroll
        for (int j = 0; j < 4; ++j) {
            int4 h, r;
            h.x = (wd[j] >> 0)  & 1; h.y = (wd[j] >> 8)  & 1;
            h.z = (wd[j] >> 16) & 1; h.w = (wd[j] >> 24) & 1;
            r.x = (wd[j] >> 1)  & 1; r.y = (wd[j] >> 9)  & 1;
            r.z = (wd[j] >> 17) & 1; r.w = (wd[j] >> 25) & 1;
            out4[((NN + tid * 16) >> 2) + j]     = h;
            out4[((2 * NN + tid * 16) >> 2) + j] = r;
        }
    }
    __syncthreads();
    if (tid == 0) out[3 * NN] = cnt;
}

extern "C" void kernel_launch(void* const* d_in, const int* in_sizes, int n_in,
                              void* d_out, int out_size, void* d_ws, size_t ws_size,
                              hipStream_t stream)
{
    const int* left  = (const int*)d_in[3];
    const int* right = (const int*)d_in[4];
    const unsigned char* reroll = (const unsigned char*)d_in[5];
    int* out = (int*)d_out;
    dag_eval_kernel<<<1, NT, 0, stream>>>(left, right, reroll, out);
}

// Round 8
// 32.915 us; speedup vs baseline: 1.1029x; 1.1029x over previous
//
#include <hip/hip_runtime.h>

#define NN 16384
#define NT 1024
#define PER 16

__global__ __launch_bounds__(NT) void dag_eval_kernel(
    const int* __restrict__ left,
    const int* __restrict__ right,
    const unsigned char* __restrict__ reroll_raw,
    int* __restrict__ out)
{
    __shared__ __align__(16) unsigned int  pairs[NN];       // l16|r16<<16, 64 KB
    __shared__ __align__(16) unsigned char reach[NN];       // 0/1 bytes
    __shared__ __align__(16) unsigned char state[NN + 16];  // hs|hr<<1|fin<<2; [NN..]=0
    __shared__ int flags[4];
    __shared__ int nzmask;
    __shared__ int cnt;

    const int tid = threadIdx.x;
    const int b0  = tid * PER;

    if (tid < 4)  flags[tid] = 0;
    if (tid == 0) { nzmask = 0; cnt = 0; }
    if (tid < 16) state[NN + tid] = 0;   // dummy: contributes nothing, never clears pend

    // ---- children -> registers (coalesced int4) + LDS pairs table ----
    unsigned int cpair[PER];
    {
        const int4* l4 = (const int4*)left;
        const int4* r4 = (const int4*)right;
        #pragma unroll
        for (int j = 0; j < PER / 4; ++j) {
            int4 a = l4[(b0 >> 2) + j];
            int4 b = r4[(b0 >> 2) + j];
            cpair[4*j+0] = (a.x & 0xFFFFu) | ((unsigned)b.x << 16);
            cpair[4*j+1] = (a.y & 0xFFFFu) | ((unsigned)b.y << 16);
            cpair[4*j+2] = (a.z & 0xFFFFu) | ((unsigned)b.z << 16);
            cpair[4*j+3] = (a.w & 0xFFFFu) | ((unsigned)b.w << 16);
            *(uint4*)&pairs[b0 + 4*j] = make_uint4(cpair[4*j+0], cpair[4*j+1],
                                                   cpair[4*j+2], cpair[4*j+3]);
        }
    }

    // ---- leaf_is_reroll layout probe (first 16 KB safe for all layouts) ----
    {
        uint4 v = ((const uint4*)reroll_raw)[tid];
        unsigned int t = v.x | v.y | v.z | v.w;
        unsigned int m = 0;
        if (t & 0x000000FFu) m |= 1u;
        if (t & 0x0000FF00u) m |= 2u;
        if (t & 0x00FF0000u) m |= 4u;
        if (t & 0xFF000000u) m |= 8u;
        if (m) atomicOr(&nzmask, (int)m);
    }
    *(uint4*)&reach[b0] = make_uint4(0u, 0u, 0u, 0u);
    __syncthreads();

    const int mask   = nzmask;
    const int layout = ((mask & ~1) == 0) ? 0 : (((mask & 3) == 0) ? 1 : 2);
    const int*   ri = (const int*)reroll_raw;
    const float* rf = (const float*)reroll_raw;

    // ---- backward init: leaf bits + pending-children mask ----
    int sreg[PER];
    unsigned int todo = 0, pend = 0;
    #pragma unroll
    for (int k = 0; k < PER; ++k) {
        int c0 = (int)(short)(cpair[k] & 0xFFFFu);
        int c1 = (int)(short)(cpair[k] >> 16);
        int s = 0;
        unsigned int p2 = 0;
        if (c0 < 0) {
            int id = -c0 - 1;
            bool rr = (layout == 2) ? (reroll_raw[id] != 0)
                     : (layout == 1) ? (rf[id] != 0.0f)
                                     : (ri[id] != 0);
            s |= rr ? 2 : 1;
        } else p2 |= 1u;
        if (c1 < 0) {
            int id = -c1 - 1;
            bool rr = (layout == 2) ? (reroll_raw[id] != 0)
                     : (layout == 1) ? (rf[id] != 0.0f)
                                     : (ri[id] != 0);
            s |= rr ? 2 : 1;
        } else p2 |= 2u;
        if (p2 == 0u || s == 3) s |= 4;          // final at init
        else { todo |= 1u << k; pend |= p2 << (2 * k); }
        sreg[k] = s;
        state[b0 + k] = (unsigned char)s;
    }
    if (tid == 0) reach[0] = 1;
    __syncthreads();

    // ---- merged fixpoint: 2-level fwd push + 2-level memoized bwd pull ----
    unsigned int pushed = 0, mm = 0;
    for (int w = 0; w < 600; ++w) {
        bool ch = false;

        // forward: poll own 16 bytes, push children+grandchildren (read-checked)
        uint4 rv = *(const uint4*)&reach[b0];
        mm  =  ((rv.x * 0x01020408u) >> 24) & 0xFu;
        mm |= (((rv.y * 0x01020408u) >> 24) & 0xFu) << 4;
        mm |= (((rv.z * 0x01020408u) >> 24) & 0xFu) << 8;
        mm |= (((rv.w * 0x01020408u) >> 24) & 0xFu) << 12;
        unsigned int newp = mm & ~pushed;
        if (newp) {
            pushed |= newp;
            #pragma unroll
            for (int k = 0; k < PER; ++k) {
                if ((newp >> k) & 1u) {
                    int c0 = (int)(short)(cpair[k] & 0xFFFFu);
                    int c1 = (int)(short)(cpair[k] >> 16);
                    if (c0 > 0) {
                        if (reach[c0] == 0) { reach[c0] = 1; ch = true; }
                        unsigned int pr = pairs[c0];
                        int g0 = (int)(short)(pr & 0xFFFFu);
                        int g1 = (int)(short)(pr >> 16);
                        if (g0 > 0 && reach[g0] == 0) { reach[g0] = 1; ch = true; }
                        if (g1 > 0 && reach[g1] == 0) { reach[g1] = 1; ch = true; }
                    }
                    if (c1 > 0) {
                        if (reach[c1] == 0) { reach[c1] = 1; ch = true; }
                        unsigned int pr = pairs[c1];
                        int g0 = (int)(short)(pr & 0xFFFFu);
                        int g1 = (int)(short)(pr >> 16);
                        if (g0 > 0 && reach[g0] == 0) { reach[g0] = 1; ch = true; }
                        if (g1 > 0 && reach[g1] == 0) { reach[g1] = 1; ch = true; }
                    }
                }
            }
        }

        // backward: pending-masked 2-level gather
        if (todo) {
            #pragma unroll
            for (int k = 0; k < PER; ++k) {
                if ((todo >> k) & 1u) {
                    unsigned int p2 = (pend >> (2 * k)) & 3u;
                    int c0 = (int)(short)(cpair[k] & 0xFFFFu);
                    int c1 = (int)(short)(cpair[k] >> 16);
                    int sl = state[(p2 & 1u) ? c0 : NN];
                    int sr = state[(p2 & 2u) ? c1 : NN];
                    int ns = sreg[k] | (sl & 3) | (sr & 3);
                    unsigned int np2 = p2;
                    if ((p2 & 1u) && (sl & 4)) np2 &= ~1u;
                    if ((p2 & 2u) && (sr & 4)) np2 &= ~2u;
                    if (np2 & 1u) {               // left child pending: dig grands
                        unsigned int pr = pairs[c0];
                        int g0 = (int)(short)(pr & 0xFFFFu);
                        int g1 = (int)(short)(pr >> 16);
                        int s0 = (g0 > 0) ? (int)state[g0] : 4;
                        int s1 = (g1 > 0) ? (int)state[g1] : 4;
                        ns |= (s0 & 3) | (s1 & 3);
                        if (s0 & s1 & 4) np2 &= ~1u;
                    }
                    if (np2 & 2u) {               // right child pending
                        unsigned int pr = pairs[c1];
                        int g0 = (int)(short)(pr & 0xFFFFu);
                        int g1 = (int)(short)(pr >> 16);
                        int s0 = (g0 > 0) ? (int)state[g0] : 4;
                        int s1 = (g1 > 0) ? (int)state[g1] : 4;
                        ns |= (s0 & 3) | (s1 & 3);
                        if (s0 & s1 & 4) np2 &= ~2u;
                    }
                    bool fin = (np2 == 0u) || ((ns & 3) == 3);
                    if (fin) { ns |= 4; todo &= ~(1u << k); }
                    pend = (pend & ~(3u << (2 * k))) | (np2 << (2 * k));
                    if (ns != sreg[k]) {
                        sreg[k] = ns;
                        state[b0 + k] = (unsigned char)ns;
                        ch = true;
                    }
                }
            }
        }

        if (ch) flags[w & 3] = 1;
        __syncthreads();                       // single barrier per sweep
        int f = flags[w & 3];
        if (tid == 0) flags[(w + 2) & 3] = 0;  // >=1 barrier before slot reuse
        if (!f) break;
    }

    // ---- count: wave shuffle reduce, one atomic per wave ----
    int cc = __popc(mm);
    #pragma unroll
    for (int off = 32; off; off >>= 1) cc += __shfl_down(cc, off);
    if ((tid & 63) == 0) atomicAdd(&cnt, cc);

    // ---- outputs from registers, int4 stores ----
    int4* out4 = (int4*)out;
    #pragma unroll
    for (int j = 0; j < PER / 4; ++j) {
        int4 a, h, r;
        a.x = (mm >> (4*j+0)) & 1; a.y = (mm >> (4*j+1)) & 1;
        a.z = (mm >> (4*j+2)) & 1; a.w = (mm >> (4*j+3)) & 1;
        h.x =  sreg[4*j+0] & 1;       h.y =  sreg[4*j+1] & 1;
        h.z =  sreg[4*j+2] & 1;       h.w =  sreg[4*j+3] & 1;
        r.x = (sreg[4*j+0] >> 1) & 1; r.y = (sreg[4*j+1] >> 1) & 1;
        r.z = (sreg[4*j+2] >> 1) & 1; r.w = (sreg[4*j+3] >> 1) & 1;
        out4[(b0 >> 2) + j]            = a;
        out4[((NN + b0) >> 2) + j]     = h;
        out4[((2 * NN + b0) >> 2) + j] = r;
    }
    __syncthreads();
    if (tid == 0) out[3 * NN] = cnt;
}

extern "C" void kernel_launch(void* const* d_in, const int* in_sizes, int n_in,
                              void* d_out, int out_size, void* d_ws, size_t ws_size,
                              hipStream_t stream)
{
    const int* left  = (const int*)d_in[3];
    const int* right = (const int*)d_in[4];
    const unsigned char* reroll = (const unsigned char*)d_in[5];
    int* out = (int*)d_out;
    dag_eval_kernel<<<1, NT, 0, stream>>>(left, right, reroll, out);
}